// Round 13
// baseline (101.636 us; speedup 1.0000x reference)
//
#include <hip/hip_runtime.h>
#include <type_traits>

typedef __attribute__((ext_vector_type(4))) float f32x4;
typedef __attribute__((ext_vector_type(8))) short s16x8;

__device__ __forceinline__ unsigned short f2bf(float f) {
    unsigned int u = __builtin_bit_cast(unsigned int, f);
    u += 0x7fffu + ((u >> 16) & 1u);           // round-to-nearest-even
    return (unsigned short)(u >> 16);
}

// packed f32x2 -> bf16x2 (RNE), one HW instr
__device__ __forceinline__ unsigned cvtpk(float lo, float hi) {
    unsigned r;
    asm("v_cvt_pk_bf16_f32 %0, %1, %2" : "=v"(r) : "v"(lo), "v"(hi));
    return r;
}

__device__ __forceinline__ void gload_lds16(const void* g, void* l) {
    __builtin_amdgcn_global_load_lds(
        (const __attribute__((address_space(1))) void*)g,
        (__attribute__((address_space(3))) void*)l, 16, 0, 0);
}

// LDS tile section (bf16, 64 k = 128 B/row): byte = row*128 + ((chunk^(row&7))<<4)
template<int ROWS, int WAVES>
__device__ __forceinline__ void stage_lds(const unsigned short* __restrict__ src,
                                          int ld, int row0, int k0,
                                          char* lds, int wid, int lane) {
    const int subrow = lane >> 3;
    const int gchunk = (lane & 7) ^ subrow;  // inverse swizzle on source
    #pragma unroll
    for (int p = 0; p < ROWS / (WAVES * 8); ++p) {
        const int r0 = (p * WAVES + wid) * 8;
        const int gr = row0 + r0 + subrow;
        const char* g = (const char*)(src + (size_t)gr * ld + k0) + gchunk * 16;
        gload_lds16(g, lds + r0 * 128);
    }
}

__device__ __forceinline__ int xcd_swizzle(int bid, int nwg) {
    const int q = nwg >> 3, r = nwg & 7;
    const int xcd = bid & 7, idx = bid >> 3;
    return (xcd < r ? xcd * (q + 1) : r * (q + 1) + (xcd - r) * q) + idx;
}

// ---------------------------------------------------------------------------
// MEGA (single launch, NO cooperative API): 504 blocks x 512 thr, 72 KiB LDS,
// __launch_bounds__(512,4) -> 2 blocks/CU -> 512 slots >= 504: all blocks
// co-resident, so a software semaphore is deadlock-safe.
//   Writers (bid<256): phase A = C1 tile (g1 math, 512-thr staging, MFMA on
//     waves 0..3), then threadfence + release-atomicAdd(sem).
//   All valid blocks: loadB(0)+writeB BEFORE spinning (E cold-miss hides
//     under phase A), acquire-spin sem==256, then the R11-validated phase-B
//     loop (counted vmcnt; ledger: entry A(t)=2; +B(t+1)=5 -> vmcnt(5) drains
//     A(t); lgkm(0); s_barrier; stage A(t+1); MFMA; writeB(t+1)).
// C1 is bit-identical across replays -> stale-cache lines are benign.
// ---------------------------------------------------------------------------
__global__ __launch_bounds__(512, 4) void mega(const float* __restrict__ x,
                                               const float* __restrict__ E,
                                               const float* __restrict__ W,
                                               float* __restrict__ out,
                                               unsigned short* __restrict__ C1,
                                               int* __restrict__ sem) {
    constexpr int MF = 2, NF = 5, BM = 128, BN = 160;
    constexpr int N = 20000, K = 512, NSTEP = K / 64;
    constexpr int ABUF = BM * 128;                 // 16384
    constexpr int BUF = (BM + BN) * 128;           // 36864
    __shared__ __align__(16) char lds[2 * BUF];    // 72 KiB

    const int bid = (int)blockIdx.x;
    const int tid = threadIdx.x, lane = tid & 63, wid = tid >> 6;   // 8 waves
    const int wm = wid >> 1, wn = wid & 1;
    const int lr = lane & 15, lg = lane >> 4;

    // phase-B geometry
    const int xcd = bid & 7, idx = bid >> 3;
    const bool valid = !(xcd >= 4 && idx >= 62);   // invalid = bids 500..503
    const int nb = valid ? ((xcd < 4 ? xcd * 63 : 252 + (xcd - 4) * 62) + idx) : 0;
    const int m0 = (nb & 3) * BM;                  // 4 consecutive nb share E panel
    const int n0 = (nb >> 2) * BN;
    const int arow_base = wm * 32, brow_base = wn * 80;
    const int r_in = tid >> 4, c4 = tid & 15;      // B stage: 32 row-slots x 16

    f32x4 breg[5];
    auto loadB = [&](int k0) {
        #pragma unroll
        for (int p = 0; p < 5; ++p)
            breg[p] = *reinterpret_cast<const f32x4*>(
                E + (size_t)(n0 + p * 32 + r_in) * 512 + k0 + c4 * 4);
    };
    auto writeB = [&](char* B) {
        #pragma unroll
        for (int p = 0; p < 5; ++p) {
            const int row = p * 32 + r_in;
            const unsigned lo = cvtpk(breg[p].x, breg[p].y);
            const unsigned hi = cvtpk(breg[p].z, breg[p].w);
            const int byte = row * 128 + (((c4 >> 1) ^ (row & 7)) << 4) + (c4 & 1) * 8;
            *reinterpret_cast<uint2*>(B + byte) = make_uint2(lo, hi);
        }
    };

    if (bid < 256) {
        // ============== phase A: one 32x32 C1 tile, K=1024, BK=128 =========
        constexpr int SEC = 4096, PBUF = 4 * SEC;  // 2 x 16 KiB phase buffers
        const int sbid = xcd_swizzle(bid, 256);
        const int am0 = (sbid & 15) * 32, an0 = (sbid >> 4) * 32;
        const int rowA = tid >> 4, ksA = (tid & 15) * 8;   // 32 rows x 8 k/thr
        const int nB = tid & 31,  ksB = (tid >> 5) * 8;    // 32 cols x 8 k/thr
        f32x4 va[2]; float wb[8];
        auto loadPh = [&](int k0) {
            const float* pa = x + (size_t)(am0 + rowA) * 1024 + k0 + ksA;
            va[0] = *reinterpret_cast<const f32x4*>(pa);
            va[1] = *reinterpret_cast<const f32x4*>(pa + 4);
            #pragma unroll
            for (int i = 0; i < 8; ++i)
                wb[i] = W[(size_t)(k0 + ksB + i) * 512 + an0 + nB];
        };
        auto writePh = [&](char* buf) {
            uint4 uA = { cvtpk(va[0].x, va[0].y), cvtpk(va[0].z, va[0].w),
                         cvtpk(va[1].x, va[1].y), cvtpk(va[1].z, va[1].w) };
            const int sA = ksA >> 6, cA = (ksA & 63) >> 3;
            *reinterpret_cast<uint4*>(buf + sA * SEC + rowA * 128 + ((cA ^ (rowA & 7)) << 4)) = uA;
            uint4 uB = { cvtpk(wb[0], wb[1]), cvtpk(wb[2], wb[3]),
                         cvtpk(wb[4], wb[5]), cvtpk(wb[6], wb[7]) };
            const int sB = ksB >> 6, cB = (ksB & 63) >> 3;
            *reinterpret_cast<uint4*>(buf + 2 * SEC + sB * SEC + nB * 128 + ((cB ^ (nB & 7)) << 4)) = uB;
        };
        f32x4 acc1 = {0.f, 0.f, 0.f, 0.f};
        loadPh(0); writePh(lds);
        __syncthreads();
        #pragma unroll 1
        for (int ph = 0; ph < 8; ++ph) {
            char* curp = lds + (ph & 1) * PBUF;
            char* nxtp = lds + ((ph + 1) & 1) * PBUF;
            if (ph < 7) loadPh((ph + 1) * 128);    // in flight over compute
            if (wid < 4) {                          // 2x2 waves, 16x16 each
                #pragma unroll
                for (int sec = 0; sec < 2; ++sec) {
                    #pragma unroll
                    for (int kk = 0; kk < 2; ++kk) {
                        const int c = kk * 4 + lg;
                        const int ra = wm * 16 + lr, rb = wn * 16 + lr;
                        s16x8 a = *reinterpret_cast<const s16x8*>(
                            curp + sec * SEC + ra * 128 + ((c ^ (ra & 7)) << 4));
                        s16x8 b = *reinterpret_cast<const s16x8*>(
                            curp + 2 * SEC + sec * SEC + rb * 128 + ((c ^ (rb & 7)) << 4));
                        acc1 = __builtin_amdgcn_mfma_f32_16x16x32_bf16(a, b, acc1, 0, 0, 0);
                    }
                }
            }
            if (ph < 7) writePh(nxtp);             // cvt+ds_write late (T14)
            __syncthreads();
        }
        if (wid < 4) {                              // C/D: col=lane&15 [m89]
            const int gcol = an0 + wn * 16 + lr;
            const int grow0 = am0 + wm * 16 + lg * 4;
            #pragma unroll
            for (int r = 0; r < 4; ++r)
                C1[(size_t)(grow0 + r) * 512 + gcol] = f2bf(acc1[r]);
        }
        __threadfence();                            // device-visible C1
        __syncthreads();
        if (tid == 0)
            __hip_atomic_fetch_add(sem, 1, __ATOMIC_RELEASE, __HIP_MEMORY_SCOPE_AGENT);
    }

    if (!valid) return;                             // bids 500..503 (readers only)

    // ======= B(0) prologue BEFORE the wait: E miss hides under phase A =====
    loadB(0);
    writeB(lds + ABUF);                             // own-block LDS; phase A done
    if (tid == 0) {
        while (__hip_atomic_load(sem, __ATOMIC_ACQUIRE, __HIP_MEMORY_SCOPE_AGENT) < 256)
            __builtin_amdgcn_s_sleep(16);
    }
    __syncthreads();                                // C1 ready grid-wide

    // ================= phase B: out tile 128x160 = C1 @ E^T ===============
    stage_lds<BM, 8>(C1, K, m0, 0, lds, wid, lane); // A(0): vm=2 outstanding

    f32x4 acc[MF][NF] = {};

    #pragma unroll 1
    for (int t = 0; t < NSTEP; ++t) {
        char* cur = lds + (t & 1) * BUF;
        char* nxt = lds + ((t + 1) & 1) * BUF;
        if (t < NSTEP - 1) {
            loadB((t + 1) * 64);                    // B(t+1) regs, in flight
            asm volatile("s_waitcnt vmcnt(5)" ::: "memory");   // A(t) landed
        } else {
            asm volatile("s_waitcnt vmcnt(0)" ::: "memory");
        }
        asm volatile("s_waitcnt lgkmcnt(0)" ::: "memory");     // publish ds_writes
        __builtin_amdgcn_s_barrier();               // tile t complete; nxt free
        if (t < NSTEP - 1)
            stage_lds<BM, 8>(C1, K, m0, (t + 1) * 64, nxt, wid, lane);  // A(t+1)

        #pragma unroll
        for (int kk = 0; kk < 2; ++kk) {            // kk-interleaved: low regs
            const int c = kk * 4 + lg;
            s16x8 af[MF], bfr[NF];
            #pragma unroll
            for (int f = 0; f < MF; ++f) {
                const int row = arow_base + f * 16 + lr;
                af[f] = *reinterpret_cast<const s16x8*>(cur + row * 128 + ((c ^ (row & 7)) << 4));
            }
            #pragma unroll
            for (int f = 0; f < NF; ++f) {
                const int row = brow_base + f * 16 + lr;
                bfr[f] = *reinterpret_cast<const s16x8*>(cur + ABUF + row * 128 + ((c ^ (row & 7)) << 4));
            }
            __builtin_amdgcn_s_setprio(1);
            #pragma unroll
            for (int mi = 0; mi < MF; ++mi)
                #pragma unroll
                for (int ni = 0; ni < NF; ++ni)
                    acc[mi][ni] = __builtin_amdgcn_mfma_f32_16x16x32_bf16(
                        af[mi], bfr[ni], acc[mi][ni], 0, 0, 0);
            __builtin_amdgcn_s_setprio(0);
        }

        if (t < NSTEP - 1)
            writeB(nxt + ABUF);                     // cvt+write B(t+1) (late)
    }

    // epilogue: C/D layout col = lane&15, row = (lane>>4)*4 + reg   [m89]
    #pragma unroll
    for (int mi = 0; mi < MF; ++mi)
        #pragma unroll
        for (int ni = 0; ni < NF; ++ni) {
            const int gcol = n0 + brow_base + ni * 16 + lr;
            const int grow0 = m0 + arow_base + mi * 16 + lg * 4;
            #pragma unroll
            for (int r = 0; r < 4; ++r)
                out[(size_t)(grow0 + r) * N + gcol] = acc[mi][ni][r];
        }
}

// ---------------------------------------------------------------------------

extern "C" void kernel_launch(void* const* d_in, const int* in_sizes, int n_in,
                              void* d_out, int out_size, void* d_ws, size_t ws_size,
                              hipStream_t stream) {
    const float* x = (const float*)d_in[0];     // [512,1024]
    const float* E = (const float*)d_in[1];     // [20000,512]
    const float* W = (const float*)d_in[2];     // [1024,512]
    float* out = (float*)d_out;                 // [512,20000]

    unsigned short* C1 = (unsigned short*)d_ws;               // 512 KiB
    int* sem = (int*)((char*)d_ws + 524288);

    hipMemsetAsync(sem, 0, 4, stream);          // zero semaphore (capture-legal)
    mega<<<504, 512, 0, stream>>>(x, E, W, out, C1, sem);
}

// Round 14
// 62.604 us; speedup vs baseline: 1.6235x; 1.6235x over previous
//
#include <hip/hip_runtime.h>
#include <type_traits>

typedef __attribute__((ext_vector_type(4))) float f32x4;
typedef __attribute__((ext_vector_type(8))) short s16x8;

__device__ __forceinline__ unsigned short f2bf(float f) {
    unsigned int u = __builtin_bit_cast(unsigned int, f);
    u += 0x7fffu + ((u >> 16) & 1u);           // round-to-nearest-even
    return (unsigned short)(u >> 16);
}

// packed f32x2 -> bf16x2 (RNE), one HW instr
__device__ __forceinline__ unsigned cvtpk(float lo, float hi) {
    unsigned r;
    asm("v_cvt_pk_bf16_f32 %0, %1, %2" : "=v"(r) : "v"(lo), "v"(hi));
    return r;
}

__device__ __forceinline__ void gload_lds16(const void* g, void* l) {
    __builtin_amdgcn_global_load_lds(
        (const __attribute__((address_space(1))) void*)g,
        (__attribute__((address_space(3))) void*)l, 16, 0, 0);
}

// LDS tile section (bf16, 64 k = 128 B/row): byte = row*128 + ((chunk^(row&7))<<4)
template<int ROWS, int WAVES>
__device__ __forceinline__ void stage_lds(const unsigned short* __restrict__ src,
                                          int ld, int row0, int k0,
                                          char* lds, int wid, int lane) {
    const int subrow = lane >> 3;
    const int gchunk = (lane & 7) ^ subrow;  // inverse swizzle on source
    #pragma unroll
    for (int p = 0; p < ROWS / (WAVES * 8); ++p) {
        const int r0 = (p * WAVES + wid) * 8;
        const int gr = row0 + r0 + subrow;
        const char* g = (const char*)(src + (size_t)gr * ld + k0) + gchunk * 16;
        gload_lds16(g, lds + r0 * 128);
    }
}

__device__ __forceinline__ int xcd_swizzle(int bid, int nwg) {
    const int q = nwg >> 3, r = nwg & 7;
    const int xcd = bid & 7, idx = bid >> 3;
    return (xcd < r ? xcd * (q + 1) : r * (q + 1) + (xcd - r) * q) + idx;
}

// ---------------------------------------------------------------------------
// K1: fused prep+GEMM1.  C1[512,512] = bf16( x[512,1024]f32 @ W[1024,512]f32 )
// 32x32 tiles, 256 blocks, BK=128/phase, 8 phases, T14 dbuf. (validated R8-R12)
// ---------------------------------------------------------------------------
__global__ __launch_bounds__(256) void fused_g1(const float* __restrict__ x,
                                                const float* __restrict__ W,
                                                unsigned short* __restrict__ C1) {
    constexpr int SEC = 4096;                  // one 64-k section: 32 rows * 128 B
    constexpr int PBUF = 4 * SEC;
    __shared__ __align__(16) char lds[2 * PBUF];   // 32 KiB

    const int tid = threadIdx.x;
    const int bid = xcd_swizzle((int)blockIdx.x, 256);
    const int m0 = (bid & 15) * 32, n0 = (bid >> 4) * 32;

    const int lane = tid & 63, wid = tid >> 6;
    const int wm = wid >> 1, wn = wid & 1;
    const int lr = lane & 15, lg = lane >> 4;

    const int rowA = tid >> 3, ksA = (tid & 7) * 16;
    const int nB = tid & 31,  ksB = (tid >> 5) * 16;

    f32x4 acc = {0.f, 0.f, 0.f, 0.f};
    f32x4 va[4];
    float wb[16];

    auto loadPh = [&](int k0) {
        const float* pa = x + (size_t)(m0 + rowA) * 1024 + k0 + ksA;
        #pragma unroll
        for (int i = 0; i < 4; ++i) va[i] = *reinterpret_cast<const f32x4*>(pa + i * 4);
        #pragma unroll
        for (int i = 0; i < 16; ++i) wb[i] = W[(size_t)(k0 + ksB + i) * 512 + n0 + nB];
    };
    auto writePh = [&](char* buf) {
        uint4 u0 = { cvtpk(va[0].x,va[0].y), cvtpk(va[0].z,va[0].w),
                     cvtpk(va[1].x,va[1].y), cvtpk(va[1].z,va[1].w) };
        uint4 u1 = { cvtpk(va[2].x,va[2].y), cvtpk(va[2].z,va[2].w),
                     cvtpk(va[3].x,va[3].y), cvtpk(va[3].z,va[3].w) };
        {
            const int sec = ksA >> 6, cin = (ksA & 63) >> 3;
            char* base = buf + sec * SEC + rowA * 128;
            *reinterpret_cast<uint4*>(base + ((( cin    ) ^ (rowA & 7)) << 4)) = u0;
            *reinterpret_cast<uint4*>(base + (((cin + 1) ^ (rowA & 7)) << 4)) = u1;
        }
        uint4 w0 = { cvtpk(wb[0],wb[1]),  cvtpk(wb[2],wb[3]),
                     cvtpk(wb[4],wb[5]),  cvtpk(wb[6],wb[7]) };
        uint4 w1 = { cvtpk(wb[8],wb[9]),  cvtpk(wb[10],wb[11]),
                     cvtpk(wb[12],wb[13]), cvtpk(wb[14],wb[15]) };
        {
            const int sec = ksB >> 6, cin = (ksB & 63) >> 3;
            char* base = buf + 2 * SEC + sec * SEC + nB * 128;
            *reinterpret_cast<uint4*>(base + ((( cin    ) ^ (nB & 7)) << 4)) = w0;
            *reinterpret_cast<uint4*>(base + (((cin + 1) ^ (nB & 7)) << 4)) = w1;
        }
    };

    loadPh(0);
    writePh(lds);
    __syncthreads();

    #pragma unroll 1
    for (int ph = 0; ph < 8; ++ph) {
        char* cur = lds + (ph & 1) * PBUF;
        char* nxt = lds + ((ph + 1) & 1) * PBUF;
        if (ph < 7) loadPh((ph + 1) * 128);
        #pragma unroll
        for (int sec = 0; sec < 2; ++sec) {
            const char* As = cur + sec * SEC;
            const char* Bs = cur + 2 * SEC + sec * SEC;
            #pragma unroll
            for (int kk = 0; kk < 2; ++kk) {
                const int c = kk * 4 + lg;
                const int ra = wm * 16 + lr, rb = wn * 16 + lr;
                s16x8 a = *reinterpret_cast<const s16x8*>(As + ra * 128 + ((c ^ (ra & 7)) << 4));
                s16x8 b = *reinterpret_cast<const s16x8*>(Bs + rb * 128 + ((c ^ (rb & 7)) << 4));
                acc = __builtin_amdgcn_mfma_f32_16x16x32_bf16(a, b, acc, 0, 0, 0);
            }
        }
        if (ph < 7) writePh(nxt);
        __syncthreads();
    }

    const int gcol = n0 + wn * 16 + lr;                // C/D: col=lane&15 [m89]
    const int grow0 = m0 + wm * 16 + lg * 4;
    #pragma unroll
    for (int r = 0; r < 4; ++r)
        C1[(size_t)(grow0 + r) * 512 + gcol] = f2bf(acc[r]);
}

// ---------------------------------------------------------------------------
// K2: GEMM2  out[512,20000] = C1 @ E^T (f32). Tile 128x160, BK=64, 8 K-steps.
// 512 threads = 8 waves (4m x 2n; MF=2 NF=5), 72 KiB LDS, 2 blocks/CU.
// R11 structure + 2-DEEP B register prefetch (two named banks, 2x-unrolled
// loop for static indexing — rule 20). Ledger per step t (verified):
//   entry outstanding [B(t+1)=5, A(t)=2]; +loadB(t+2)=5 -> 12;
//   vmcnt(5) drains B(t+1)+A(t), leaves B(t+2); lgkm(0) publishes my
//   writeB(t) ds_writes; s_barrier => buf[t&1] complete, nxt free;
//   stageA(t+1)->nxt; writeB(t+1)->nxt (bank drained by this step's vmcnt);
//   MFMA on cur.  t>=6: no new loads -> vmcnt(0) (free, loads are old).
// ---------------------------------------------------------------------------
__global__ __launch_bounds__(512, 4) void gemm2fused(const unsigned short* __restrict__ C1,
                                                     const float* __restrict__ E,
                                                     float* __restrict__ out) {
    constexpr int MF = 2, NF = 5, BM = 128, BN = 160;
    constexpr int N = 20000, K = 512, NSTEP = K / 64;
    constexpr int ABUF = BM * 128;                 // 16384
    constexpr int BUF = (BM + BN) * 128;           // 36864
    __shared__ __align__(16) char lds[2 * BUF];    // 72 KiB

    const int xcd = (int)blockIdx.x & 7, idx = (int)blockIdx.x >> 3;
    if (xcd >= 4 && idx >= 62) return;
    const int nb = (xcd < 4 ? xcd * 63 : 252 + (xcd - 4) * 62) + idx;
    const int m0 = (nb & 3) * BM;                  // 4 consecutive nb share E panel
    const int n0 = (nb >> 2) * BN;

    const int tid = threadIdx.x, lane = tid & 63, wid = tid >> 6;
    const int wm = wid >> 1, wn = wid & 1;         // 4 x 2 wave grid
    const int arow_base = wm * 32;
    const int brow_base = wn * 80;
    const int lr = lane & 15, lg = lane >> 4;

    const int r_in = tid >> 4, c4 = tid & 15;      // B stage: 32 row-slots x 16

    f32x4 acc[MF][NF] = {};
    f32x4 bregA[5], bregB[5];                      // two static banks

    auto loadB = [&](f32x4 (&b)[5], int k0) {
        #pragma unroll
        for (int p = 0; p < 5; ++p)
            b[p] = *reinterpret_cast<const f32x4*>(
                E + (size_t)(n0 + p * 32 + r_in) * 512 + k0 + c4 * 4);
    };
    auto writeB = [&](const f32x4 (&b)[5], char* B) {
        #pragma unroll
        for (int p = 0; p < 5; ++p) {
            const int row = p * 32 + r_in;
            const unsigned lo = cvtpk(b[p].x, b[p].y);
            const unsigned hi = cvtpk(b[p].z, b[p].w);
            const int byte = row * 128 + (((c4 >> 1) ^ (row & 7)) << 4) + (c4 & 1) * 8;
            *reinterpret_cast<uint2*>(B + byte) = make_uint2(lo, hi);
        }
    };
    auto computeStep = [&](const char* cur) {
        #pragma unroll
        for (int kk = 0; kk < 2; ++kk) {
            const int c = kk * 4 + lg;
            s16x8 af[MF], bfr[NF];
            #pragma unroll
            for (int f = 0; f < MF; ++f) {
                const int row = arow_base + f * 16 + lr;
                af[f] = *reinterpret_cast<const s16x8*>(cur + row * 128 + ((c ^ (row & 7)) << 4));
            }
            #pragma unroll
            for (int f = 0; f < NF; ++f) {
                const int row = brow_base + f * 16 + lr;
                bfr[f] = *reinterpret_cast<const s16x8*>(cur + ABUF + row * 128 + ((c ^ (row & 7)) << 4));
            }
            __builtin_amdgcn_s_setprio(1);
            #pragma unroll
            for (int mi = 0; mi < MF; ++mi)
                #pragma unroll
                for (int ni = 0; ni < NF; ++ni)
                    acc[mi][ni] = __builtin_amdgcn_mfma_f32_16x16x32_bf16(
                        af[mi], bfr[ni], acc[mi][ni], 0, 0, 0);
            __builtin_amdgcn_s_setprio(0);
        }
    };

    // prologue: B(0)->bankA, B(1)->bankB, A(0) staged; write B(0)
    loadB(bregA, 0);                                   // vm: 5
    loadB(bregB, 64);                                  // vm: 10
    stage_lds<BM, 8>(C1, K, m0, 0, lds, wid, lane);    // vm: 12
    writeB(bregA, lds + ABUF);                         // drains B(0) (reg dep)

    // 2x-unrolled main loop: even t uses bankA for load / bankB for write.
    #pragma unroll 1
    for (int d = 0; d < NSTEP / 2; ++d) {
        // ---- t = 2d (even): cur = buf0, nxt = buf1
        {
            const int t = 2 * d;
            char* cur = lds;
            char* nxt = lds + BUF;
            if (t < NSTEP - 2) {
                loadB(bregA, (t + 2) * 64);            // B(t+2) -> bankA
                asm volatile("s_waitcnt vmcnt(5)" ::: "memory");  // A(t)+B(t+1) landed
            } else {
                asm volatile("s_waitcnt vmcnt(0)" ::: "memory");
            }
            asm volatile("s_waitcnt lgkmcnt(0)" ::: "memory");
            __builtin_amdgcn_s_barrier();              // buf0 complete; buf1 free
            if (t < NSTEP - 1) {
                stage_lds<BM, 8>(C1, K, m0, (t + 1) * 64, nxt, wid, lane);
                writeB(bregB, nxt + ABUF);             // B(t+1), already landed
            }
            computeStep(cur);
        }
        // ---- t = 2d+1 (odd): cur = buf1, nxt = buf0
        {
            const int t = 2 * d + 1;
            char* cur = lds + BUF;
            char* nxt = lds;
            if (t < NSTEP - 2) {
                loadB(bregB, (t + 2) * 64);            // B(t+2) -> bankB
                asm volatile("s_waitcnt vmcnt(5)" ::: "memory");
            } else {
                asm volatile("s_waitcnt vmcnt(0)" ::: "memory");
            }
            asm volatile("s_waitcnt lgkmcnt(0)" ::: "memory");
            __builtin_amdgcn_s_barrier();              // buf1 complete; buf0 free
            if (t < NSTEP - 1) {
                stage_lds<BM, 8>(C1, K, m0, (t + 1) * 64, nxt, wid, lane);
                writeB(bregA, nxt + ABUF);             // B(t+1)
            }
            computeStep(cur);
        }
    }

    // epilogue: C/D layout col = lane&15, row = (lane>>4)*4 + reg   [m89]
    #pragma unroll
    for (int mi = 0; mi < MF; ++mi)
        #pragma unroll
        for (int ni = 0; ni < NF; ++ni) {
            const int gcol = n0 + brow_base + ni * 16 + lr;
            const int grow0 = m0 + arow_base + mi * 16 + lg * 4;
            #pragma unroll
            for (int r = 0; r < 4; ++r)
                out[(size_t)(grow0 + r) * N + gcol] = acc[mi][ni][r];
        }
}

// ---------------------------------------------------------------------------

extern "C" void kernel_launch(void* const* d_in, const int* in_sizes, int n_in,
                              void* d_out, int out_size, void* d_ws, size_t ws_size,
                              hipStream_t stream) {
    const float* x = (const float*)d_in[0];     // [512,1024]
    const float* E = (const float*)d_in[1];     // [20000,512]
    const float* W = (const float*)d_in[2];     // [1024,512]
    float* out = (float*)d_out;                 // [512,20000]

    unsigned short* C1 = (unsigned short*)d_ws; // 512 KiB

    // K1: fused prep + GEMM1
    fused_g1<<<256, 256, 0, stream>>>(x, W, C1);

    // K2: out = C1 @ E^T, 2-deep B prefetch, 504 blocks (500 real)
    gemm2fused<<<504, 512, 0, stream>>>(C1, E, out);
}

// Round 15
// 32.438 us; speedup vs baseline: 3.1332x; 1.9299x over previous
//
#include <hip/hip_runtime.h>
#include <type_traits>

typedef __attribute__((ext_vector_type(4))) float f32x4;
typedef __attribute__((ext_vector_type(8))) short s16x8;

__device__ __forceinline__ unsigned short f2bf(float f) {
    unsigned int u = __builtin_bit_cast(unsigned int, f);
    u += 0x7fffu + ((u >> 16) & 1u);           // round-to-nearest-even
    return (unsigned short)(u >> 16);
}

// packed f32x2 -> bf16x2 (RNE), one HW instr
__device__ __forceinline__ unsigned cvtpk(float lo, float hi) {
    unsigned r;
    asm("v_cvt_pk_bf16_f32 %0, %1, %2" : "=v"(r) : "v"(lo), "v"(hi));
    return r;
}

__device__ __forceinline__ void gload_lds16(const void* g, void* l) {
    __builtin_amdgcn_global_load_lds(
        (const __attribute__((address_space(1))) void*)g,
        (__attribute__((address_space(3))) void*)l, 16, 0, 0);
}

// ---------------------------------------------------------------------------
// LDS tile section (bf16, 64 k-elems = 128 B per row):
//   byte(row, chunk) = row*128 + ((chunk ^ (row&7)) << 4)
// Staged via global_load_lds: linear LDS dest, pre-swizzled source chunk.
// ---------------------------------------------------------------------------
template<int ROWS, int WAVES>
__device__ __forceinline__ void stage_lds(const unsigned short* __restrict__ src,
                                          int ld, int row0, int k0,
                                          char* lds, int wid, int lane) {
    const int subrow = lane >> 3;            // 0..7
    const int gchunk = (lane & 7) ^ subrow;  // inverse swizzle on source
    #pragma unroll
    for (int p = 0; p < ROWS / (WAVES * 8); ++p) {
        const int r0 = (p * WAVES + wid) * 8;
        const int gr = row0 + r0 + subrow;
        const char* g = (const char*)(src + (size_t)gr * ld + k0) + gchunk * 16;
        gload_lds16(g, lds + r0 * 128);      // wave-uniform base + lane*16
    }
}

__device__ __forceinline__ int xcd_swizzle(int bid, int nwg) {
    const int q = nwg >> 3, r = nwg & 7;
    const int xcd = bid & 7, idx = bid >> 3;
    return (xcd < r ? xcd * (q + 1) : r * (q + 1) + (xcd - r) * q) + idx;
}

// ---------------------------------------------------------------------------
// K1: fused prep+GEMM1.  C1[512,512] = bf16( x[512,1024]f32 @ W[1024,512]f32 )
// In-kernel cvt (v_cvt_pk) + W-transpose via ds_write addressing. Tile 32x32,
// 256 blocks (all CUs), BK=128/phase (2 sections), 8 phases, T14 dbuf.
// (validated R8-R12: ~3.5 us, latency-bound)
// ---------------------------------------------------------------------------
__global__ __launch_bounds__(256) void fused_g1(const float* __restrict__ x,
                                                const float* __restrict__ W,
                                                unsigned short* __restrict__ C1) {
    constexpr int SEC = 4096;                  // one 64-k section: 32 rows * 128 B
    constexpr int PBUF = 4 * SEC;              // phase buf: A(2 sec) + B(2 sec)
    __shared__ __align__(16) char lds[2 * PBUF];   // 32 KiB

    const int tid = threadIdx.x;
    const int bid = xcd_swizzle((int)blockIdx.x, 256);
    const int m0 = (bid & 15) * 32, n0 = (bid >> 4) * 32;

    const int lane = tid & 63, wid = tid >> 6;
    const int wm = wid >> 1, wn = wid & 1;
    const int lr = lane & 15, lg = lane >> 4;

    const int rowA = tid >> 3, ksA = (tid & 7) * 16;   // A: 32 rows x 16 k / thread
    const int nB = tid & 31,  ksB = (tid >> 5) * 16;   // B: 32 cols x 16 k / thread

    f32x4 acc = {0.f, 0.f, 0.f, 0.f};
    f32x4 va[4];
    float wb[16];

    auto loadPh = [&](int k0) {
        const float* pa = x + (size_t)(m0 + rowA) * 1024 + k0 + ksA;
        #pragma unroll
        for (int i = 0; i < 4; ++i) va[i] = *reinterpret_cast<const f32x4*>(pa + i * 4);
        #pragma unroll
        for (int i = 0; i < 16; ++i) wb[i] = W[(size_t)(k0 + ksB + i) * 512 + n0 + nB];
    };
    auto writePh = [&](char* buf) {
        uint4 u0 = { cvtpk(va[0].x,va[0].y), cvtpk(va[0].z,va[0].w),
                     cvtpk(va[1].x,va[1].y), cvtpk(va[1].z,va[1].w) };
        uint4 u1 = { cvtpk(va[2].x,va[2].y), cvtpk(va[2].z,va[2].w),
                     cvtpk(va[3].x,va[3].y), cvtpk(va[3].z,va[3].w) };
        {
            const int sec = ksA >> 6, cin = (ksA & 63) >> 3;
            char* base = buf + sec * SEC + rowA * 128;
            *reinterpret_cast<uint4*>(base + ((( cin    ) ^ (rowA & 7)) << 4)) = u0;
            *reinterpret_cast<uint4*>(base + (((cin + 1) ^ (rowA & 7)) << 4)) = u1;
        }
        uint4 w0 = { cvtpk(wb[0],wb[1]),  cvtpk(wb[2],wb[3]),
                     cvtpk(wb[4],wb[5]),  cvtpk(wb[6],wb[7]) };
        uint4 w1 = { cvtpk(wb[8],wb[9]),  cvtpk(wb[10],wb[11]),
                     cvtpk(wb[12],wb[13]), cvtpk(wb[14],wb[15]) };
        {
            const int sec = ksB >> 6, cin = (ksB & 63) >> 3;
            char* base = buf + 2 * SEC + sec * SEC + nB * 128;
            *reinterpret_cast<uint4*>(base + ((( cin    ) ^ (nB & 7)) << 4)) = w0;
            *reinterpret_cast<uint4*>(base + (((cin + 1) ^ (nB & 7)) << 4)) = w1;
        }
    };

    loadPh(0);
    writePh(lds);
    __syncthreads();

    #pragma unroll 1
    for (int ph = 0; ph < 8; ++ph) {
        char* cur = lds + (ph & 1) * PBUF;
        char* nxt = lds + ((ph + 1) & 1) * PBUF;
        if (ph < 7) loadPh((ph + 1) * 128);            // loads in flight over compute
        #pragma unroll
        for (int sec = 0; sec < 2; ++sec) {
            const char* As = cur + sec * SEC;
            const char* Bs = cur + 2 * SEC + sec * SEC;
            #pragma unroll
            for (int kk = 0; kk < 2; ++kk) {
                const int c = kk * 4 + lg;
                const int ra = wm * 16 + lr, rb = wn * 16 + lr;
                s16x8 a = *reinterpret_cast<const s16x8*>(As + ra * 128 + ((c ^ (ra & 7)) << 4));
                s16x8 b = *reinterpret_cast<const s16x8*>(Bs + rb * 128 + ((c ^ (rb & 7)) << 4));
                acc = __builtin_amdgcn_mfma_f32_16x16x32_bf16(a, b, acc, 0, 0, 0);
            }
        }
        if (ph < 7) writePh(nxt);                      // cvt+ds_write late (T14)
        __syncthreads();
    }

    const int gcol = n0 + wn * 16 + lr;                // C/D: col=lane&15 [m89]
    const int grow0 = m0 + wm * 16 + lg * 4;
    #pragma unroll
    for (int r = 0; r < 4; ++r)
        C1[(size_t)(grow0 + r) * 512 + gcol] = f2bf(acc[r]);
}

// ---------------------------------------------------------------------------
// K2: GEMM2  out[512,20000] = C1 @ E^T (f32). Tile 128x160, BK=64, 8 K-steps.
// 512 threads = 8 waves (4m x 2n; per-wave 32x80, MF=2 NF=5) -> 72 KiB LDS,
// <=128 VGPR, 2 blocks/CU = 16 waves/CU (4/SIMD).
// A (C1 bf16): global_load_lds (2/wave/step).  B (E f32): coalesced global ->
// regs (5 dwordx4/thread) -> cvt_pk -> ds_write into freed buffer (T14).
// One raw s_barrier per K-step; counted vmcnt (B stays in flight across it).
// Ledger/iter t: entry outstanding A(t)=2; +B(t+1)=5 -> 7; vmcnt(5) drains
// A(t); lgkm(0) publishes my B(t) ds_writes; s_barrier => tile t complete,
// nxt free; +A(t+1)=2; compute cur; writeB(t+1)->nxt (compiler drains B regs).
// Grid 504 = 8 XCDs x {63,63,63,63,62,62,62,62}; 20000 = 125*160, no N edge.
// (measured best: R9 = 32.28 us total)
// ---------------------------------------------------------------------------
__global__ __launch_bounds__(512, 4) void gemm2fused(const unsigned short* __restrict__ C1,
                                                     const float* __restrict__ E,
                                                     float* __restrict__ out) {
    constexpr int MF = 2, NF = 5, BM = 128, BN = 160;
    constexpr int N = 20000, K = 512, NSTEP = K / 64;
    constexpr int ABUF = BM * 128;                 // 16384
    constexpr int BUF = (BM + BN) * 128;           // 36864
    __shared__ __align__(16) char lds[2 * BUF];    // 72 KiB

    const int xcd = (int)blockIdx.x & 7, idx = (int)blockIdx.x >> 3;
    if (xcd >= 4 && idx >= 62) return;
    const int nb = (xcd < 4 ? xcd * 63 : 252 + (xcd - 4) * 62) + idx;
    const int m0 = (nb & 3) * BM;                  // 4 consecutive nb share E panel
    const int n0 = (nb >> 2) * BN;

    const int tid = threadIdx.x, lane = tid & 63, wid = tid >> 6;  // 0..7
    const int wm = wid >> 1, wn = wid & 1;         // 4 x 2 wave grid
    const int arow_base = wm * 32;                 // 0/32/64/96
    const int brow_base = wn * 80;                 // 0/80
    const int lr = lane & 15, lg = lane >> 4;

    const int r_in = tid >> 4, c4 = tid & 15;      // B stage: 32 row-slots x 16

    f32x4 acc[MF][NF] = {};
    f32x4 breg[5];

    auto loadB = [&](int k0) {
        #pragma unroll
        for (int p = 0; p < 5; ++p)
            breg[p] = *reinterpret_cast<const f32x4*>(
                E + (size_t)(n0 + p * 32 + r_in) * 512 + k0 + c4 * 4);
    };
    auto writeB = [&](char* Bs) {
        #pragma unroll
        for (int p = 0; p < 5; ++p) {
            const int row = p * 32 + r_in;
            const unsigned lo = cvtpk(breg[p].x, breg[p].y);
            const unsigned hi = cvtpk(breg[p].z, breg[p].w);
            const int byte = row * 128 + (((c4 >> 1) ^ (row & 7)) << 4) + (c4 & 1) * 8;
            *reinterpret_cast<uint2*>(Bs + byte) = make_uint2(lo, hi);
        }
    };

    loadB(0);                                          // vm: B0=5
    stage_lds<BM, 8>(C1, K, m0, 0, lds, wid, lane);    // vm: +A0=2 -> 7
    writeB(lds + ABUF);                                // compiler waits breg only

    #pragma unroll 1
    for (int t = 0; t < NSTEP; ++t) {
        char* cur = lds + (t & 1) * BUF;
        char* nxt = lds + ((t + 1) & 1) * BUF;
        if (t < NSTEP - 1) {
            loadB((t + 1) * 64);                       // B(t+1) regs, in flight
            asm volatile("s_waitcnt vmcnt(5)" ::: "memory");   // A(t) landed
        } else {
            asm volatile("s_waitcnt vmcnt(0)" ::: "memory");
        }
        asm volatile("s_waitcnt lgkmcnt(0)" ::: "memory");     // publish ds_writes
        __builtin_amdgcn_s_barrier();                  // tile t complete; nxt free
        if (t < NSTEP - 1)
            stage_lds<BM, 8>(C1, K, m0, (t + 1) * 64, nxt, wid, lane);  // A(t+1)

        // compute tile t: kk-halves interleaved to keep frag regs low
        #pragma unroll
        for (int kk = 0; kk < 2; ++kk) {
            const int c = kk * 4 + lg;
            s16x8 af[MF], bfr[NF];
            #pragma unroll
            for (int f = 0; f < MF; ++f) {
                const int row = arow_base + f * 16 + lr;
                af[f] = *reinterpret_cast<const s16x8*>(cur + row * 128 + ((c ^ (row & 7)) << 4));
            }
            #pragma unroll
            for (int f = 0; f < NF; ++f) {
                const int row = brow_base + f * 16 + lr;
                bfr[f] = *reinterpret_cast<const s16x8*>(cur + ABUF + row * 128 + ((c ^ (row & 7)) << 4));
            }
            __builtin_amdgcn_s_setprio(1);
            #pragma unroll
            for (int mi = 0; mi < MF; ++mi)
                #pragma unroll
                for (int ni = 0; ni < NF; ++ni)
                    acc[mi][ni] = __builtin_amdgcn_mfma_f32_16x16x32_bf16(
                        af[mi], bfr[ni], acc[mi][ni], 0, 0, 0);
            __builtin_amdgcn_s_setprio(0);
        }

        if (t < NSTEP - 1)
            writeB(nxt + ABUF);                        // cvt+write B(t+1) (late)
    }

    // epilogue: C/D layout col = lane&15, row = (lane>>4)*4 + reg   [m89]
    #pragma unroll
    for (int mi = 0; mi < MF; ++mi)
        #pragma unroll
        for (int ni = 0; ni < NF; ++ni) {
            const int gcol = n0 + brow_base + ni * 16 + lr;
            const int grow0 = m0 + arow_base + mi * 16 + lg * 4;
            #pragma unroll
            for (int r = 0; r < 4; ++r)
                out[(size_t)(grow0 + r) * N + gcol] = acc[mi][ni][r];
        }
}

// ---------------------------------------------------------------------------

extern "C" void kernel_launch(void* const* d_in, const int* in_sizes, int n_in,
                              void* d_out, int out_size, void* d_ws, size_t ws_size,
                              hipStream_t stream) {
    const float* x = (const float*)d_in[0];     // [512,1024]
    const float* E = (const float*)d_in[1];     // [20000,512]
    const float* W = (const float*)d_in[2];     // [1024,512]
    float* out = (float*)d_out;                 // [512,20000]

    unsigned short* C1 = (unsigned short*)d_ws; // 512 KiB

    // K1: fused prep + GEMM1 (reads x, W f32 directly)
    fused_g1<<<256, 256, 0, stream>>>(x, W, C1);

    // K2: out = C1 @ E^T, 8-wave blocks, 504 launched (500 real)
    gemm2fused<<<504, 512, 0, stream>>>(C1, E, out);
}

// Round 16
// 31.758 us; speedup vs baseline: 3.2003x; 1.0214x over previous
//
#include <hip/hip_runtime.h>
#include <type_traits>

typedef __attribute__((ext_vector_type(4))) float f32x4;
typedef __attribute__((ext_vector_type(8))) short s16x8;

__device__ __forceinline__ unsigned short f2bf(float f) {
    unsigned int u = __builtin_bit_cast(unsigned int, f);
    u += 0x7fffu + ((u >> 16) & 1u);           // round-to-nearest-even
    return (unsigned short)(u >> 16);
}

// packed f32x2 -> bf16x2 (RNE), one HW instr
__device__ __forceinline__ unsigned cvtpk(float lo, float hi) {
    unsigned r;
    asm("v_cvt_pk_bf16_f32 %0, %1, %2" : "=v"(r) : "v"(lo), "v"(hi));
    return r;
}

__device__ __forceinline__ void gload_lds16(const void* g, void* l) {
    __builtin_amdgcn_global_load_lds(
        (const __attribute__((address_space(1))) void*)g,
        (__attribute__((address_space(3))) void*)l, 16, 0, 0);
}

// ---------------------------------------------------------------------------
// LDS tile section (bf16, 64 k-elems = 128 B per row):
//   byte(row, chunk) = row*128 + ((chunk ^ (row&7)) << 4)
// Staged via global_load_lds: linear LDS dest, pre-swizzled source chunk.
// ---------------------------------------------------------------------------
template<int ROWS, int WAVES>
__device__ __forceinline__ void stage_lds(const unsigned short* __restrict__ src,
                                          int ld, int row0, int k0,
                                          char* lds, int wid, int lane) {
    const int subrow = lane >> 3;            // 0..7
    const int gchunk = (lane & 7) ^ subrow;  // inverse swizzle on source
    #pragma unroll
    for (int p = 0; p < ROWS / (WAVES * 8); ++p) {
        const int r0 = (p * WAVES + wid) * 8;
        const int gr = row0 + r0 + subrow;
        const char* g = (const char*)(src + (size_t)gr * ld + k0) + gchunk * 16;
        gload_lds16(g, lds + r0 * 128);      // wave-uniform base + lane*16
    }
}

__device__ __forceinline__ int xcd_swizzle(int bid, int nwg) {
    const int q = nwg >> 3, r = nwg & 7;
    const int xcd = bid & 7, idx = bid >> 3;
    return (xcd < r ? xcd * (q + 1) : r * (q + 1) + (xcd - r) * q) + idx;
}

// ---------------------------------------------------------------------------
// K1: fused prep+GEMM1.  C1[512,512] = bf16( x[512,1024]f32 @ W[1024,512]f32 )
// 32x32 tiles, 256 blocks, BK=128/phase, 8 phases, T14 dbuf. (validated)
// ---------------------------------------------------------------------------
__global__ __launch_bounds__(256) void fused_g1(const float* __restrict__ x,
                                                const float* __restrict__ W,
                                                unsigned short* __restrict__ C1) {
    constexpr int SEC = 4096;                  // one 64-k section: 32 rows * 128 B
    constexpr int PBUF = 4 * SEC;              // phase buf: A(2 sec) + B(2 sec)
    __shared__ __align__(16) char lds[2 * PBUF];   // 32 KiB

    const int tid = threadIdx.x;
    const int bid = xcd_swizzle((int)blockIdx.x, 256);
    const int m0 = (bid & 15) * 32, n0 = (bid >> 4) * 32;

    const int lane = tid & 63, wid = tid >> 6;
    const int wm = wid >> 1, wn = wid & 1;
    const int lr = lane & 15, lg = lane >> 4;

    const int rowA = tid >> 3, ksA = (tid & 7) * 16;   // A: 32 rows x 16 k / thread
    const int nB = tid & 31,  ksB = (tid >> 5) * 16;   // B: 32 cols x 16 k / thread

    f32x4 acc = {0.f, 0.f, 0.f, 0.f};
    f32x4 va[4];
    float wb[16];

    auto loadPh = [&](int k0) {
        const float* pa = x + (size_t)(m0 + rowA) * 1024 + k0 + ksA;
        #pragma unroll
        for (int i = 0; i < 4; ++i) va[i] = *reinterpret_cast<const f32x4*>(pa + i * 4);
        #pragma unroll
        for (int i = 0; i < 16; ++i) wb[i] = W[(size_t)(k0 + ksB + i) * 512 + n0 + nB];
    };
    auto writePh = [&](char* buf) {
        uint4 u0 = { cvtpk(va[0].x,va[0].y), cvtpk(va[0].z,va[0].w),
                     cvtpk(va[1].x,va[1].y), cvtpk(va[1].z,va[1].w) };
        uint4 u1 = { cvtpk(va[2].x,va[2].y), cvtpk(va[2].z,va[2].w),
                     cvtpk(va[3].x,va[3].y), cvtpk(va[3].z,va[3].w) };
        {
            const int sec = ksA >> 6, cin = (ksA & 63) >> 3;
            char* base = buf + sec * SEC + rowA * 128;
            *reinterpret_cast<uint4*>(base + ((( cin    ) ^ (rowA & 7)) << 4)) = u0;
            *reinterpret_cast<uint4*>(base + (((cin + 1) ^ (rowA & 7)) << 4)) = u1;
        }
        uint4 w0 = { cvtpk(wb[0],wb[1]),  cvtpk(wb[2],wb[3]),
                     cvtpk(wb[4],wb[5]),  cvtpk(wb[6],wb[7]) };
        uint4 w1 = { cvtpk(wb[8],wb[9]),  cvtpk(wb[10],wb[11]),
                     cvtpk(wb[12],wb[13]), cvtpk(wb[14],wb[15]) };
        {
            const int sec = ksB >> 6, cin = (ksB & 63) >> 3;
            char* base = buf + 2 * SEC + sec * SEC + nB * 128;
            *reinterpret_cast<uint4*>(base + ((( cin    ) ^ (nB & 7)) << 4)) = w0;
            *reinterpret_cast<uint4*>(base + (((cin + 1) ^ (nB & 7)) << 4)) = w1;
        }
    };

    loadPh(0);
    writePh(lds);
    __syncthreads();

    #pragma unroll 1
    for (int ph = 0; ph < 8; ++ph) {
        char* cur = lds + (ph & 1) * PBUF;
        char* nxt = lds + ((ph + 1) & 1) * PBUF;
        if (ph < 7) loadPh((ph + 1) * 128);            // loads in flight over compute
        #pragma unroll
        for (int sec = 0; sec < 2; ++sec) {
            const char* As = cur + sec * SEC;
            const char* Bs = cur + 2 * SEC + sec * SEC;
            #pragma unroll
            for (int kk = 0; kk < 2; ++kk) {
                const int c = kk * 4 + lg;
                const int ra = wm * 16 + lr, rb = wn * 16 + lr;
                s16x8 a = *reinterpret_cast<const s16x8*>(As + ra * 128 + ((c ^ (ra & 7)) << 4));
                s16x8 b = *reinterpret_cast<const s16x8*>(Bs + rb * 128 + ((c ^ (rb & 7)) << 4));
                acc = __builtin_amdgcn_mfma_f32_16x16x32_bf16(a, b, acc, 0, 0, 0);
            }
        }
        if (ph < 7) writePh(nxt);                      // cvt+ds_write late (T14)
        __syncthreads();
    }

    const int gcol = n0 + wn * 16 + lr;                // C/D: col=lane&15 [m89]
    const int grow0 = m0 + wm * 16 + lg * 4;
    #pragma unroll
    for (int r = 0; r < 4; ++r)
        C1[(size_t)(grow0 + r) * 512 + gcol] = f2bf(acc[r]);
}

// ---------------------------------------------------------------------------
// K2: GEMM2  out[512,20000] = C1 @ E^T (f32). Tile 256x160, BK=64, 8 K-steps.
// 512 threads = 8 waves (4m x 2n; per-wave 64x80, MF=4 NF=5).
// Grid 250 = 2 m-blocks x 125 n-tiles -> 1 block/CU (104 KiB LDS), one round.
// Rationale vs 128x160: per-CU LDS reads/step 224 -> 144 b128 (B-frag reads
// amortize over 2x M-rows) — LDS pipe is the binding per-step constraint.
// Same validated sync template; ledger per iter t:
//   entry outstanding A(t)=4; +B(t+1)=5 -> 9; vmcnt(5) drains A(t);
//   lgkm(0) publishes my B(t) ds_writes; s_barrier => tile t complete, nxt
//   free; +A(t+1)=4; compute cur; writeB(t+1)->nxt (reg dep drains B).
// ---------------------------------------------------------------------------
__global__ __launch_bounds__(512, 2) void gemm2fused(const unsigned short* __restrict__ C1,
                                                     const float* __restrict__ E,
                                                     float* __restrict__ out) {
    constexpr int MF = 4, NF = 5, BM = 256, BN = 160;
    constexpr int N = 20000, K = 512, NSTEP = K / 64;
    constexpr int ABUF = BM * 128;                 // 32768
    constexpr int BUF = (BM + BN) * 128;           // 53248
    __shared__ __align__(16) char lds[2 * BUF];    // 104 KiB -> 1 block/CU

    const int nb = xcd_swizzle((int)blockIdx.x, 250);   // bijective (q=31,r=2)
    const int m0 = (nb & 1) * BM;                  // 2 consecutive nb share E panel
    const int n0 = (nb >> 1) * BN;

    const int tid = threadIdx.x, lane = tid & 63, wid = tid >> 6;  // 0..7
    const int wm = wid >> 1, wn = wid & 1;         // 4 x 2 wave grid
    const int arow_base = wm * 64;                 // 0/64/128/192
    const int brow_base = wn * 80;                 // 0/80
    const int lr = lane & 15, lg = lane >> 4;

    const int r_in = tid >> 4, c4 = tid & 15;      // B stage: 32 row-slots x 16

    f32x4 acc[MF][NF] = {};
    f32x4 breg[5];

    auto loadB = [&](int k0) {
        #pragma unroll
        for (int p = 0; p < 5; ++p)
            breg[p] = *reinterpret_cast<const f32x4*>(
                E + (size_t)(n0 + p * 32 + r_in) * 512 + k0 + c4 * 4);
    };
    auto writeB = [&](char* Bs) {
        #pragma unroll
        for (int p = 0; p < 5; ++p) {
            const int row = p * 32 + r_in;
            const unsigned lo = cvtpk(breg[p].x, breg[p].y);
            const unsigned hi = cvtpk(breg[p].z, breg[p].w);
            const int byte = row * 128 + (((c4 >> 1) ^ (row & 7)) << 4) + (c4 & 1) * 8;
            *reinterpret_cast<uint2*>(Bs + byte) = make_uint2(lo, hi);
        }
    };

    loadB(0);                                          // vm: B0=5
    stage_lds<BM, 8>(C1, K, m0, 0, lds, wid, lane);    // vm: +A0=4 -> 9
    writeB(lds + ABUF);                                // compiler waits breg only

    #pragma unroll 1
    for (int t = 0; t < NSTEP; ++t) {
        char* cur = lds + (t & 1) * BUF;
        char* nxt = lds + ((t + 1) & 1) * BUF;
        if (t < NSTEP - 1) {
            loadB((t + 1) * 64);                       // B(t+1) regs, in flight
            asm volatile("s_waitcnt vmcnt(5)" ::: "memory");   // A(t) landed
        } else {
            asm volatile("s_waitcnt vmcnt(0)" ::: "memory");
        }
        asm volatile("s_waitcnt lgkmcnt(0)" ::: "memory");     // publish ds_writes
        __builtin_amdgcn_s_barrier();                  // tile t complete; nxt free
        if (t < NSTEP - 1)
            stage_lds<BM, 8>(C1, K, m0, (t + 1) * 64, nxt, wid, lane);  // A(t+1)

        // compute tile t: kk-halves interleaved to keep frag regs low
        #pragma unroll
        for (int kk = 0; kk < 2; ++kk) {
            const int c = kk * 4 + lg;
            s16x8 af[MF], bfr[NF];
            #pragma unroll
            for (int f = 0; f < MF; ++f) {
                const int row = arow_base + f * 16 + lr;
                af[f] = *reinterpret_cast<const s16x8*>(cur + row * 128 + ((c ^ (row & 7)) << 4));
            }
            #pragma unroll
            for (int f = 0; f < NF; ++f) {
                const int row = brow_base + f * 16 + lr;
                bfr[f] = *reinterpret_cast<const s16x8*>(cur + ABUF + row * 128 + ((c ^ (row & 7)) << 4));
            }
            __builtin_amdgcn_s_setprio(1);
            #pragma unroll
            for (int mi = 0; mi < MF; ++mi)
                #pragma unroll
                for (int ni = 0; ni < NF; ++ni)
                    acc[mi][ni] = __builtin_amdgcn_mfma_f32_16x16x32_bf16(
                        af[mi], bfr[ni], acc[mi][ni], 0, 0, 0);
            __builtin_amdgcn_s_setprio(0);
        }

        if (t < NSTEP - 1)
            writeB(nxt + ABUF);                        // cvt+write B(t+1) (late)
    }

    // epilogue: C/D layout col = lane&15, row = (lane>>4)*4 + reg   [m89]
    #pragma unroll
    for (int mi = 0; mi < MF; ++mi)
        #pragma unroll
        for (int ni = 0; ni < NF; ++ni) {
            const int gcol = n0 + brow_base + ni * 16 + lr;
            const int grow0 = m0 + arow_base + mi * 16 + lg * 4;
            #pragma unroll
            for (int r = 0; r < 4; ++r)
                out[(size_t)(grow0 + r) * N + gcol] = acc[mi][ni][r];
        }
}

// ---------------------------------------------------------------------------

extern "C" void kernel_launch(void* const* d_in, const int* in_sizes, int n_in,
                              void* d_out, int out_size, void* d_ws, size_t ws_size,
                              hipStream_t stream) {
    const float* x = (const float*)d_in[0];     // [512,1024]
    const float* E = (const float*)d_in[1];     // [20000,512]
    const float* W = (const float*)d_in[2];     // [1024,512]
    float* out = (float*)d_out;                 // [512,20000]

    unsigned short* C1 = (unsigned short*)d_ws; // 512 KiB

    // K1: fused prep + GEMM1 (reads x, W f32 directly)
    fused_g1<<<256, 256, 0, stream>>>(x, W, C1);

    // K2: out = C1 @ E^T, 256x160 tiles, 250 blocks (1/CU), one round
    gemm2fused<<<250, 512, 0, stream>>>(C1, E, out);
}